// Round 5
// baseline (2512.176 us; speedup 1.0000x reference)
//
#include <hip/hip_runtime.h>

#define NDIM 128

// ---------------- edge-index normalization ----------------
// int64 edge_index => odd 32-bit words are 0; int32 => odd words are random
// node ids. ONE block samples 4096 edges; no global atomics (R2: full-E
// single-address atomic detection cost 108 us).
__global__ __launch_bounds__(256) void detect_kernel(
    const int* __restrict__ raw, int* __restrict__ flag, int E) {
    __shared__ int any_nz;
    if (threadIdx.x == 0) any_nz = 0;
    __syncthreads();
    int local = 0;
    const int samples = (E < 4096) ? E : 4096;
#pragma unroll
    for (int j = 0; j < 16; ++j) {
        int i = threadIdx.x * 16 + j;
        if (i < samples) local |= raw[2 * i + 1];
    }
    if (local) atomicOr(&any_nz, 1);   // LDS atomic, cheap
    __syncthreads();
    if (threadIdx.x == 0) *flag = any_nz;   // nonzero -> int32 layout
}

__global__ void convert_kernel(const int* __restrict__ raw, const int* __restrict__ flag,
                               int* __restrict__ idx, int total) {
    int i = blockIdx.x * 256 + threadIdx.x;
    if (i >= total) return;
    idx[i] = (*flag == 0) ? raw[2 * i] : raw[i];
}

// ---------------- CSR build (counting sort by dst) ----------------
__global__ void hist_kernel(const int* __restrict__ idx, int* __restrict__ deg, int E) {
    int i = blockIdx.x * 256 + threadIdx.x;
    if (i < E) atomicAdd(&deg[idx[E + i]], 1);  // dst row
}

// --- device-wide exclusive scan of deg, 3 kernels, tile = 1024 elements ---
__global__ __launch_bounds__(256) void deg_reduce_kernel(
    const int* __restrict__ deg, int* __restrict__ partials, int n) {
    const int base = blockIdx.x * 1024;
    const int tid = threadIdx.x;
    int s = 0;
#pragma unroll
    for (int j = 0; j < 4; ++j) {
        int i = base + tid * 4 + j;
        if (i < n) s += deg[i];
    }
#pragma unroll
    for (int off = 32; off; off >>= 1) s += __shfl_down(s, off);
    __shared__ int ws[4];
    if ((tid & 63) == 0) ws[tid >> 6] = s;
    __syncthreads();
    if (tid == 0) partials[blockIdx.x] = ws[0] + ws[1] + ws[2] + ws[3];
}

__global__ void scan_partials_kernel(int* __restrict__ partials, int nb,
                                     int* __restrict__ row_start, int n) {
    __shared__ int sh[1024];
    const int tid = threadIdx.x;  // 1024 threads
    int v = (tid < nb) ? partials[tid] : 0;
    sh[tid] = v;
    __syncthreads();
    for (int off = 1; off < 1024; off <<= 1) {
        int a = sh[tid];
        int b = (tid >= off) ? sh[tid - off] : 0;
        __syncthreads();
        sh[tid] = a + b;
        __syncthreads();
    }
    if (tid < nb) partials[tid] = (tid == 0) ? 0 : sh[tid - 1];  // exclusive block offset
    if (tid == 0) row_start[n] = sh[1023];                       // total edge count
}

__global__ __launch_bounds__(256) void deg_downsweep_kernel(
    const int* __restrict__ deg, const int* __restrict__ partials,
    int* __restrict__ row_start, int* __restrict__ cursor,
    float* __restrict__ inv_deg, int n) {
    const int base = blockIdx.x * 1024;
    const int tid = threadIdx.x;
    const int i0 = base + tid * 4;
    int d[4];
    int s = 0;
#pragma unroll
    for (int j = 0; j < 4; ++j) {
        int i = i0 + j;
        d[j] = (i < n) ? deg[i] : 0;
        s += d[j];
    }
    const int lane = tid & 63;
    int incl = s;
#pragma unroll
    for (int off = 1; off < 64; off <<= 1) {
        int t = __shfl_up(incl, off);
        if (lane >= off) incl += t;
    }
    __shared__ int wsum[4];
    if (lane == 63) wsum[tid >> 6] = incl;
    __syncthreads();
    int woff = 0;
    const int w = tid >> 6;
    for (int k = 0; k < w; ++k) woff += wsum[k];
    int excl = incl - s + woff + partials[blockIdx.x];
#pragma unroll
    for (int j = 0; j < 4; ++j) {
        int i = i0 + j;
        if (i < n) {
            row_start[i] = excl;
            cursor[i] = excl;
            inv_deg[i] = 1.0f / (float)max(d[j], 1);
            excl += d[j];
        }
    }
}

__global__ void scatter_kernel(const int* __restrict__ idx, int* __restrict__ cursor,
                               int* __restrict__ sorted_src, int E) {
    int i = blockIdx.x * 256 + threadIdx.x;
    if (i < E) {
        int d = idx[E + i];
        int p = atomicAdd(&cursor[d], 1);
        sorted_src[p] = idx[i];
    }
}

// ---------------- mean aggregation (CSR gather-reduce) ----------------
// 32 threads per node, each owns a float4 column slice.
__global__ __launch_bounds__(256) void aggregate_kernel(
    const float* __restrict__ x, const int* __restrict__ row_start,
    const int* __restrict__ sorted_src, const float* __restrict__ inv_deg,
    float* __restrict__ aggr, int n) {
    int gid = blockIdx.x * 256 + threadIdx.x;
    int node = gid >> 5;
    if (node >= n) return;
    int q = (gid & 31) << 2;
    int beg = row_start[node];
    int end = row_start[node + 1];
    float4 acc = make_float4(0.f, 0.f, 0.f, 0.f);
    for (int e = beg; e < end; ++e) {
        int s = sorted_src[e];
        const float4 v = *(const float4*)(x + (size_t)s * NDIM + q);
        acc.x += v.x; acc.y += v.y; acc.z += v.z; acc.w += v.w;
    }
    float inv = inv_deg[node];
    acc.x *= inv; acc.y *= inv; acc.z *= inv; acc.w *= inv;
    *(float4*)(aggr + (size_t)node * NDIM + q) = acc;
}

// ------- fused layer GEMM v3: Y = Ag@Wl + X@Wr + b (+relu) -------
// One-wave (64-thread) blocks, 64x64 output tile, per-thread 8x8 acc.
// Intensity 4 FLOP/LDS-float (R4 lesson: v2's 4x4 tile at 2.0 was LDS-bound).
// Grid (ceil(n/64), 2): 1564 blocks ~ 6/CU, fine-grained balance.
// Register-prefetch of next K-chunk overlaps global latency with compute.
// Inner LDS reads: W cols split as tx*4 and 32+tx*4 -> conflict-free;
// A rows 8ty -> 2-way (free per m136).
__global__ __launch_bounds__(64, 2) void gemm_kernel(
    const float* __restrict__ Ag, const float* __restrict__ X,
    const float* __restrict__ Wl, const float* __restrict__ Wr,
    const float* __restrict__ bias, float* __restrict__ Y, int n, int do_relu) {
    __shared__ float Al[8][68];   // A^T chunk [k][row], 272B stride (16B-aligned)
    __shared__ float Ar[8][68];
    __shared__ float Sl[8][68];   // W chunk [k][col-local]
    __shared__ float Sr[8][68];
    const int lane = threadIdx.x;          // 0..63
    const int tx = lane & 7;               // col quad id
    const int ty = lane >> 3;              // row oct id
    const int row0 = blockIdx.x * 64;
    const int col0 = blockIdx.y * 64;

    int arow = row0 + lane;
    if (arow >= n) arow = n - 1;           // clamp: stays in-bounds, rows>=n never stored
    const float* __restrict__ agp = Ag + (size_t)arow * NDIM;
    const float* __restrict__ xp  = X  + (size_t)arow * NDIM;
    const int wrow = lane >> 4;            // 0..3
    const int wcg  = (lane & 15) << 2;     // 0..60
    const float* __restrict__ wlp = Wl + (size_t)wrow * NDIM + col0 + wcg;
    const float* __restrict__ wrp = Wr + (size_t)wrow * NDIM + col0 + wcg;

    float acc[8][8];
#pragma unroll
    for (int i = 0; i < 8; ++i)
#pragma unroll
        for (int j = 0; j < 8; ++j) acc[i][j] = 0.f;

    // prefetch chunk 0
    float4 pa0 = *(const float4*)(agp);
    float4 pa1 = *(const float4*)(agp + 4);
    float4 px0 = *(const float4*)(xp);
    float4 px1 = *(const float4*)(xp + 4);
    float4 pl0 = *(const float4*)(wlp);
    float4 pl1 = *(const float4*)(wlp + 4 * NDIM);
    float4 pr0 = *(const float4*)(wrp);
    float4 pr1 = *(const float4*)(wrp + 4 * NDIM);

    for (int it = 0; it < 16; ++it) {
        __syncthreads();
        Al[0][lane] = pa0.x; Al[1][lane] = pa0.y; Al[2][lane] = pa0.z; Al[3][lane] = pa0.w;
        Al[4][lane] = pa1.x; Al[5][lane] = pa1.y; Al[6][lane] = pa1.z; Al[7][lane] = pa1.w;
        Ar[0][lane] = px0.x; Ar[1][lane] = px0.y; Ar[2][lane] = px0.z; Ar[3][lane] = px0.w;
        Ar[4][lane] = px1.x; Ar[5][lane] = px1.y; Ar[6][lane] = px1.z; Ar[7][lane] = px1.w;
        *(float4*)&Sl[wrow][wcg]     = pl0;
        *(float4*)&Sl[wrow + 4][wcg] = pl1;
        *(float4*)&Sr[wrow][wcg]     = pr0;
        *(float4*)&Sr[wrow + 4][wcg] = pr1;
        __syncthreads();
        if (it < 15) {                      // prefetch next chunk during compute
            const int k0 = (it + 1) * 8;
            pa0 = *(const float4*)(agp + k0);
            pa1 = *(const float4*)(agp + k0 + 4);
            px0 = *(const float4*)(xp + k0);
            px1 = *(const float4*)(xp + k0 + 4);
            pl0 = *(const float4*)(wlp + (size_t)k0 * NDIM);
            pl1 = *(const float4*)(wlp + (size_t)(k0 + 4) * NDIM);
            pr0 = *(const float4*)(wrp + (size_t)k0 * NDIM);
            pr1 = *(const float4*)(wrp + (size_t)(k0 + 4) * NDIM);
        }
#pragma unroll
        for (int k = 0; k < 8; ++k) {
            const float4 a0 = *(const float4*)&Al[k][ty << 3];
            const float4 a1 = *(const float4*)&Al[k][(ty << 3) + 4];
            const float4 b0 = *(const float4*)&Ar[k][ty << 3];
            const float4 b1 = *(const float4*)&Ar[k][(ty << 3) + 4];
            const float4 l0 = *(const float4*)&Sl[k][tx << 2];
            const float4 l1 = *(const float4*)&Sl[k][(tx << 2) + 32];
            const float4 r0 = *(const float4*)&Sr[k][tx << 2];
            const float4 r1 = *(const float4*)&Sr[k][(tx << 2) + 32];
            const float a8[8] = {a0.x, a0.y, a0.z, a0.w, a1.x, a1.y, a1.z, a1.w};
            const float x8[8] = {b0.x, b0.y, b0.z, b0.w, b1.x, b1.y, b1.z, b1.w};
            const float l8[8] = {l0.x, l0.y, l0.z, l0.w, l1.x, l1.y, l1.z, l1.w};
            const float r8[8] = {r0.x, r0.y, r0.z, r0.w, r1.x, r1.y, r1.z, r1.w};
#pragma unroll
            for (int i = 0; i < 8; ++i)
#pragma unroll
                for (int j = 0; j < 8; ++j)
                    acc[i][j] += a8[i] * l8[j] + x8[i] * r8[j];
        }
    }

    // epilogue: cols j0..3 -> col0+tx*4, j4..7 -> col0+32+tx*4
    const float4 bb0 = *(const float4*)(bias + col0 + (tx << 2));
    const float4 bb1 = *(const float4*)(bias + col0 + 32 + (tx << 2));
    const float bl4[4] = {bb0.x, bb0.y, bb0.z, bb0.w};
    const float bh4[4] = {bb1.x, bb1.y, bb1.z, bb1.w};
#pragma unroll
    for (int i = 0; i < 8; ++i) {
        const int r = row0 + (ty << 3) + i;
        if (r < n) {
            float lo[4], hi[4];
#pragma unroll
            for (int j = 0; j < 4; ++j) {
                lo[j] = acc[i][j] + bl4[j];
                hi[j] = acc[i][j + 4] + bh4[j];
                if (do_relu) { lo[j] = fmaxf(lo[j], 0.f); hi[j] = fmaxf(hi[j], 0.f); }
            }
            *(float4*)(Y + (size_t)r * NDIM + col0 + (tx << 2)) =
                make_float4(lo[0], lo[1], lo[2], lo[3]);
            *(float4*)(Y + (size_t)r * NDIM + col0 + 32 + (tx << 2)) =
                make_float4(hi[0], hi[1], hi[2], hi[3]);
        }
    }
}

// ---------------- host launcher ----------------
extern "C" void kernel_launch(void* const* d_in, const int* in_sizes, int n_in,
                              void* d_out, int out_size, void* d_ws, size_t ws_size,
                              hipStream_t stream) {
    const float* x0   = (const float*)d_in[0];
    const int*   eraw = (const int*)d_in[1];
    const float* Wl   = (const float*)d_in[2];
    const float* bl   = (const float*)d_in[3];
    const float* Wr   = (const float*)d_in[4];
    float* out = (float*)d_out;

    const int N = in_sizes[0] / NDIM;   // 50000
    const int E = in_sizes[1] / 2;      // 600000

    auto align_up = [](size_t v) { return (v + 255) & ~(size_t)255; };
    char* p = (char*)d_ws;
    int* idx = (int*)p;                 p += align_up((size_t)2 * E * 4);
    int* deg = (int*)p;                 p += align_up((size_t)(N + 1) * 4);  // deg[N] is the flag
    int* flag = deg + N;
    int* row_start = (int*)p;           p += align_up((size_t)(N + 1) * 4);
    int* cursor = (int*)p;              p += align_up((size_t)N * 4);
    int* ssrc = (int*)p;                p += align_up((size_t)E * 4);
    float* invd = (float*)p;            p += align_up((size_t)N * 4);
    int* partials = (int*)p;            p += align_up((size_t)1024 * 4);
    float* buf0 = (float*)p;            p += align_up((size_t)N * NDIM * 4);
    float* buf1 = (float*)p;            p += align_up((size_t)N * NDIM * 4);

    const int nb = (N + 1023) / 1024;   // scan tiles

    hipMemsetAsync(deg, 0, (size_t)N * 4, stream);
    detect_kernel<<<1, 256, 0, stream>>>(eraw, flag, E);
    convert_kernel<<<(2 * E + 255) / 256, 256, 0, stream>>>(eraw, flag, idx, 2 * E);
    hist_kernel<<<(E + 255) / 256, 256, 0, stream>>>(idx, deg, E);
    deg_reduce_kernel<<<nb, 256, 0, stream>>>(deg, partials, N);
    scan_partials_kernel<<<1, 1024, 0, stream>>>(partials, nb, row_start, N);
    deg_downsweep_kernel<<<nb, 256, 0, stream>>>(deg, partials, row_start, cursor, invd, N);
    scatter_kernel<<<(E + 255) / 256, 256, 0, stream>>>(idx, cursor, ssrc, E);

    // gemm blocks cover only half the columns of their rows, so output must
    // not alias either input. Rotate gemm outputs through {out, buf1}:
    // y = {out, buf1, out, buf1, out}; aggregate always writes buf0.
    const int gm = (N + 63) / 64;
    const float* xin = x0;
    for (int l = 0; l < 5; ++l) {
        aggregate_kernel<<<(N * 32 + 255) / 256, 256, 0, stream>>>(
            xin, row_start, ssrc, invd, buf0, N);
        float* yo = (l & 1) ? buf1 : out;
        gemm_kernel<<<dim3(gm, 2), 64, 0, stream>>>(
            buf0, xin, Wl + (size_t)l * NDIM * NDIM, Wr + (size_t)l * NDIM * NDIM,
            bl + (size_t)l * NDIM, yo, N, l < 4 ? 1 : 0);
        xin = yo;
    }
}

// Round 6
// 738.752 us; speedup vs baseline: 3.4006x; 3.4006x over previous
//
#include <hip/hip_runtime.h>

#define NDIM 128

// ---------------- edge-index normalization ----------------
// int64 edge_index => odd 32-bit words are 0; int32 => odd words are random
// node ids. ONE block samples 4096 edges; no global atomics (R2: full-E
// single-address atomic detection cost 108 us).
__global__ __launch_bounds__(256) void detect_kernel(
    const int* __restrict__ raw, int* __restrict__ flag, int E) {
    __shared__ int any_nz;
    if (threadIdx.x == 0) any_nz = 0;
    __syncthreads();
    int local = 0;
    const int samples = (E < 4096) ? E : 4096;
#pragma unroll
    for (int j = 0; j < 16; ++j) {
        int i = threadIdx.x * 16 + j;
        if (i < samples) local |= raw[2 * i + 1];
    }
    if (local) atomicOr(&any_nz, 1);   // LDS atomic, cheap
    __syncthreads();
    if (threadIdx.x == 0) *flag = any_nz;   // nonzero -> int32 layout
}

__global__ void convert_kernel(const int* __restrict__ raw, const int* __restrict__ flag,
                               int* __restrict__ idx, int total) {
    int i = blockIdx.x * 256 + threadIdx.x;
    if (i >= total) return;
    idx[i] = (*flag == 0) ? raw[2 * i] : raw[i];
}

// ---------------- CSR build (counting sort by dst) ----------------
__global__ void hist_kernel(const int* __restrict__ idx, int* __restrict__ deg, int E) {
    int i = blockIdx.x * 256 + threadIdx.x;
    if (i < E) atomicAdd(&deg[idx[E + i]], 1);  // dst row
}

// --- device-wide exclusive scan of deg, 3 kernels, tile = 1024 elements ---
__global__ __launch_bounds__(256) void deg_reduce_kernel(
    const int* __restrict__ deg, int* __restrict__ partials, int n) {
    const int base = blockIdx.x * 1024;
    const int tid = threadIdx.x;
    int s = 0;
#pragma unroll
    for (int j = 0; j < 4; ++j) {
        int i = base + tid * 4 + j;
        if (i < n) s += deg[i];
    }
#pragma unroll
    for (int off = 32; off; off >>= 1) s += __shfl_down(s, off);
    __shared__ int ws[4];
    if ((tid & 63) == 0) ws[tid >> 6] = s;
    __syncthreads();
    if (tid == 0) partials[blockIdx.x] = ws[0] + ws[1] + ws[2] + ws[3];
}

__global__ void scan_partials_kernel(int* __restrict__ partials, int nb,
                                     int* __restrict__ row_start, int n) {
    __shared__ int sh[1024];
    const int tid = threadIdx.x;  // 1024 threads
    int v = (tid < nb) ? partials[tid] : 0;
    sh[tid] = v;
    __syncthreads();
    for (int off = 1; off < 1024; off <<= 1) {
        int a = sh[tid];
        int b = (tid >= off) ? sh[tid - off] : 0;
        __syncthreads();
        sh[tid] = a + b;
        __syncthreads();
    }
    if (tid < nb) partials[tid] = (tid == 0) ? 0 : sh[tid - 1];  // exclusive block offset
    if (tid == 0) row_start[n] = sh[1023];                       // total edge count
}

__global__ __launch_bounds__(256) void deg_downsweep_kernel(
    const int* __restrict__ deg, const int* __restrict__ partials,
    int* __restrict__ row_start, int* __restrict__ cursor,
    float* __restrict__ inv_deg, int n) {
    const int base = blockIdx.x * 1024;
    const int tid = threadIdx.x;
    const int i0 = base + tid * 4;
    int d[4];
    int s = 0;
#pragma unroll
    for (int j = 0; j < 4; ++j) {
        int i = i0 + j;
        d[j] = (i < n) ? deg[i] : 0;
        s += d[j];
    }
    const int lane = tid & 63;
    int incl = s;
#pragma unroll
    for (int off = 1; off < 64; off <<= 1) {
        int t = __shfl_up(incl, off);
        if (lane >= off) incl += t;
    }
    __shared__ int wsum[4];
    if (lane == 63) wsum[tid >> 6] = incl;
    __syncthreads();
    int woff = 0;
    const int w = tid >> 6;
    for (int k = 0; k < w; ++k) woff += wsum[k];
    int excl = incl - s + woff + partials[blockIdx.x];
#pragma unroll
    for (int j = 0; j < 4; ++j) {
        int i = i0 + j;
        if (i < n) {
            row_start[i] = excl;
            cursor[i] = excl;
            inv_deg[i] = 1.0f / (float)max(d[j], 1);
            excl += d[j];
        }
    }
}

__global__ void scatter_kernel(const int* __restrict__ idx, int* __restrict__ cursor,
                               int* __restrict__ sorted_src, int E) {
    int i = blockIdx.x * 256 + threadIdx.x;
    if (i < E) {
        int d = idx[E + i];
        int p = atomicAdd(&cursor[d], 1);
        sorted_src[p] = idx[i];
    }
}

// ---------------- mean aggregation (CSR gather-reduce) ----------------
// 32 threads per node, each owns a float4 column slice.
__global__ __launch_bounds__(256) void aggregate_kernel(
    const float* __restrict__ x, const int* __restrict__ row_start,
    const int* __restrict__ sorted_src, const float* __restrict__ inv_deg,
    float* __restrict__ aggr, int n) {
    int gid = blockIdx.x * 256 + threadIdx.x;
    int node = gid >> 5;
    if (node >= n) return;
    int q = (gid & 31) << 2;
    int beg = row_start[node];
    int end = row_start[node + 1];
    float4 acc = make_float4(0.f, 0.f, 0.f, 0.f);
    for (int e = beg; e < end; ++e) {
        int s = sorted_src[e];
        const float4 v = *(const float4*)(x + (size_t)s * NDIM + q);
        acc.x += v.x; acc.y += v.y; acc.z += v.z; acc.w += v.w;
    }
    float inv = inv_deg[node];
    acc.x *= inv; acc.y *= inv; acc.z *= inv; acc.w *= inv;
    *(float4*)(aggr + (size_t)node * NDIM + q) = acc;
}

// ------- fused layer GEMM v4: Y = Ag@Wl + X@Wr + b (+relu) -------
// R3 structure (256 thr, 64x128 tile, 4x8 acc, 44 VGPR — no spills) plus
// v2's verified bank-conflict fix: each thread's 8 cols read as two float4s
// at tx*4 and 64+tx*4 (2-way aliasing = free; old tx*8 was 4-way, 6.8M
// conflict cycles). R5 lesson: 8x8 acc at 64 thr spilled to scratch (1 GB
// writes/dispatch) — keep per-thread state small.
__global__ __launch_bounds__(256) void gemm_kernel(
    const float* Ag, const float* __restrict__ X,
    const float* __restrict__ Wl, const float* __restrict__ Wr,
    const float* __restrict__ bias, float* Y, int n, int do_relu) {
    __shared__ float Al[16][68];
    __shared__ float Ar[16][68];
    __shared__ float Sl[16][128];
    __shared__ float Sr[16][128];
    const int tid = threadIdx.x;
    const int tx = tid & 15;    // col group: cols {tx*4..tx*4+3, 64+tx*4..64+tx*4+3}
    const int ty = tid >> 4;    // row group: rows ty*4 .. ty*4+3
    const int row0 = blockIdx.x * 64;
    float acc[4][8];
#pragma unroll
    for (int i = 0; i < 4; ++i)
#pragma unroll
        for (int j = 0; j < 8; ++j) acc[i][j] = 0.f;

    const int lrow = tid >> 2;          // 0..63
    const int lk = (tid & 3) << 2;      // 0,4,8,12
    const int wk = tid >> 5;            // 0..7
    const int wc = (tid & 31) << 2;     // 0..124
    const int arow = row0 + lrow;

    for (int k0 = 0; k0 < NDIM; k0 += 16) {
        float4 a_l = make_float4(0.f, 0.f, 0.f, 0.f);
        float4 a_r = make_float4(0.f, 0.f, 0.f, 0.f);
        if (arow < n) {
            a_l = *(const float4*)(Ag + (size_t)arow * NDIM + k0 + lk);
            a_r = *(const float4*)(X + (size_t)arow * NDIM + k0 + lk);
        }
        const float4 wl0 = *(const float4*)(Wl + (size_t)(k0 + wk) * NDIM + wc);
        const float4 wl1 = *(const float4*)(Wl + (size_t)(k0 + wk + 8) * NDIM + wc);
        const float4 wr0 = *(const float4*)(Wr + (size_t)(k0 + wk) * NDIM + wc);
        const float4 wr1 = *(const float4*)(Wr + (size_t)(k0 + wk + 8) * NDIM + wc);
        __syncthreads();
        Al[lk + 0][lrow] = a_l.x; Al[lk + 1][lrow] = a_l.y;
        Al[lk + 2][lrow] = a_l.z; Al[lk + 3][lrow] = a_l.w;
        Ar[lk + 0][lrow] = a_r.x; Ar[lk + 1][lrow] = a_r.y;
        Ar[lk + 2][lrow] = a_r.z; Ar[lk + 3][lrow] = a_r.w;
        *(float4*)&Sl[wk][wc] = wl0;
        *(float4*)&Sl[wk + 8][wc] = wl1;
        *(float4*)&Sr[wk][wc] = wr0;
        *(float4*)&Sr[wk + 8][wc] = wr1;
        __syncthreads();
#pragma unroll 4
        for (int k = 0; k < 16; ++k) {
            const float4 av = *(const float4*)&Al[k][ty << 2];        // broadcast
            const float4 bv = *(const float4*)&Ar[k][ty << 2];
            const float4 l0 = *(const float4*)&Sl[k][tx << 2];        // 2-way (free)
            const float4 l1 = *(const float4*)&Sl[k][(tx << 2) + 64];
            const float4 r0 = *(const float4*)&Sr[k][tx << 2];
            const float4 r1 = *(const float4*)&Sr[k][(tx << 2) + 64];
            const float a4[4] = {av.x, av.y, av.z, av.w};
            const float b4[4] = {bv.x, bv.y, bv.z, bv.w};
            const float wl8[8] = {l0.x, l0.y, l0.z, l0.w, l1.x, l1.y, l1.z, l1.w};
            const float wr8[8] = {r0.x, r0.y, r0.z, r0.w, r1.x, r1.y, r1.z, r1.w};
#pragma unroll
            for (int i = 0; i < 4; ++i)
#pragma unroll
                for (int j = 0; j < 8; ++j)
                    acc[i][j] += a4[i] * wl8[j] + b4[i] * wr8[j];
        }
    }

    // epilogue: cols j0..3 -> tx*4, j4..7 -> 64+tx*4
    const float4 bb0 = *(const float4*)(bias + (tx << 2));
    const float4 bb1 = *(const float4*)(bias + (tx << 2) + 64);
    const float bl4[4] = {bb0.x, bb0.y, bb0.z, bb0.w};
    const float bh4[4] = {bb1.x, bb1.y, bb1.z, bb1.w};
#pragma unroll
    for (int i = 0; i < 4; ++i) {
        const int r = row0 + (ty << 2) + i;
        if (r < n) {
            float lo[4], hi[4];
#pragma unroll
            for (int j = 0; j < 4; ++j) {
                lo[j] = acc[i][j] + bl4[j];
                hi[j] = acc[i][j + 4] + bh4[j];
                if (do_relu) { lo[j] = fmaxf(lo[j], 0.f); hi[j] = fmaxf(hi[j], 0.f); }
            }
            *(float4*)(Y + (size_t)r * NDIM + (tx << 2)) =
                make_float4(lo[0], lo[1], lo[2], lo[3]);
            *(float4*)(Y + (size_t)r * NDIM + (tx << 2) + 64) =
                make_float4(hi[0], hi[1], hi[2], hi[3]);
        }
    }
}

// ---------------- host launcher ----------------
extern "C" void kernel_launch(void* const* d_in, const int* in_sizes, int n_in,
                              void* d_out, int out_size, void* d_ws, size_t ws_size,
                              hipStream_t stream) {
    const float* x0   = (const float*)d_in[0];
    const int*   eraw = (const int*)d_in[1];
    const float* Wl   = (const float*)d_in[2];
    const float* bl   = (const float*)d_in[3];
    const float* Wr   = (const float*)d_in[4];
    float* out = (float*)d_out;

    const int N = in_sizes[0] / NDIM;   // 50000
    const int E = in_sizes[1] / 2;      // 600000

    auto align_up = [](size_t v) { return (v + 255) & ~(size_t)255; };
    char* p = (char*)d_ws;
    int* idx = (int*)p;                 p += align_up((size_t)2 * E * 4);
    int* deg = (int*)p;                 p += align_up((size_t)(N + 1) * 4);  // deg[N] is the flag
    int* flag = deg + N;
    int* row_start = (int*)p;           p += align_up((size_t)(N + 1) * 4);
    int* cursor = (int*)p;              p += align_up((size_t)N * 4);
    int* ssrc = (int*)p;                p += align_up((size_t)E * 4);
    float* invd = (float*)p;            p += align_up((size_t)N * 4);
    int* partials = (int*)p;            p += align_up((size_t)1024 * 4);
    float* buf0 = (float*)p;            p += align_up((size_t)N * NDIM * 4);
    float* buf1 = (float*)p;            p += align_up((size_t)N * NDIM * 4);

    const int nb = (N + 1023) / 1024;   // scan tiles

    hipMemsetAsync(deg, 0, (size_t)N * 4, stream);
    detect_kernel<<<1, 256, 0, stream>>>(eraw, flag, E);
    convert_kernel<<<(2 * E + 255) / 256, 256, 0, stream>>>(eraw, flag, idx, 2 * E);
    hist_kernel<<<(E + 255) / 256, 256, 0, stream>>>(idx, deg, E);
    deg_reduce_kernel<<<nb, 256, 0, stream>>>(deg, partials, N);
    scan_partials_kernel<<<1, 1024, 0, stream>>>(partials, nb, row_start, N);
    deg_downsweep_kernel<<<nb, 256, 0, stream>>>(deg, partials, row_start, cursor, invd, N);
    scatter_kernel<<<(E + 255) / 256, 256, 0, stream>>>(idx, cursor, ssrc, E);

    // Each gemm block reads and writes only its own 64-row band, with all
    // reads before the epilogue stores -> in-place (Y == Ag) is safe.
    const float* xin = x0;
    for (int l = 0; l < 5; ++l) {
        float* ab = (l & 1) ? buf1 : buf0;          // aggregation output
        aggregate_kernel<<<(N * 32 + 255) / 256, 256, 0, stream>>>(
            xin, row_start, ssrc, invd, ab, N);
        float* yo = (l == 4) ? out : ab;
        gemm_kernel<<<(N + 63) / 64, 256, 0, stream>>>(
            ab, xin, Wl + (size_t)l * NDIM * NDIM, Wr + (size_t)l * NDIM * NDIM,
            bl + (size_t)l * NDIM, yo, N, l < 4 ? 1 : 0);
        xin = yo;
    }
}